// Round 5
// baseline (413.382 us; speedup 1.0000x reference)
//
#include <hip/hip_runtime.h>

// GRU cell, B=8192, IN=H=1024, OUT=512 — bf16 MFMA pipeline.
// R11: 1-phase-ahead register pipeline in the 8-phase GEMM1.
//  Diagnosis: phase time 1850cyc ~= MFMA(620) + LDS(500) + sync — SERIAL.
//  Cause: af/bf reused every phase -> same physical VGPRs -> next phase's
//  ds_reads WAR against the draining MFMA cluster -> LDS pipe starts only
//  after MFMA drains. Fix: two explicit fragment sets (afA/afB, bfA/bfB);
//  phase = {stage; (wait+)BAR; ds-reads for p+1 into OTHER set; MFMA(p)}.
//  reads(p+1) precede mfh(p) in program order -> both sets live -> distinct
//  registers guaranteed -> LDS reads overlap MFMA drain (m201's property).
//  All barriers carry lgkmcnt(0) (closes the cross-wave read-vs-stage race;
//  costs ~0 — reads had a full MFMA window). vmcnt waits unchanged: p3/p7
//  vmcnt(4); tail WV0@p3. Slot-validity re-verified for the shifted reads:
//  slot2 reads @p3 after WV4 (retires A2,B2), slot3 @p5 (retired same WV4),
//  slot0' @p7 after WV4 (retires A0',B0'), slot1' @next-p1 (same WV4).
// GEMM2/GEMM3 unchanged (R6 2-phase); k_prep unchanged.

typedef __bf16 bf16x8 __attribute__((ext_vector_type(8)));
typedef float floatx4 __attribute__((ext_vector_type(4)));

__device__ __forceinline__ unsigned short f2bf(float f) {
  unsigned int u = __float_as_uint(f);
  u += 0x7fffu + ((u >> 16) & 1u);
  return (unsigned short)(u >> 16);
}

__device__ __forceinline__ void gld16(const void* g, void* l) {
  // async global->LDS, 16B/lane; LDS dest = wave-uniform base + lane*16
  __builtin_amdgcn_global_load_lds(
      (__attribute__((address_space(1))) void*)g,
      (__attribute__((address_space(3))) void*)l, 16, 0, 0);
}

// pack_xh (blocks 0..8191) + cvt_all (blocks 8192..14847) in one launch
__global__ void k_prep(const float* __restrict__ x, const float* __restrict__ h,
                       unsigned short* __restrict__ XH,
                       unsigned short* __restrict__ XRH,
                       const float* __restrict__ Wz, const float* __restrict__ Wr,
                       const float* __restrict__ Wh, const float* __restrict__ Wo,
                       unsigned short* __restrict__ WZR,
                       unsigned short* __restrict__ WHb,
                       unsigned short* __restrict__ WOb) {
  if (blockIdx.x < 8192) {
    int t = blockIdx.x * blockDim.x + threadIdx.x;
    int row = t >> 8;
    int c4 = (t & 255) << 2;
    float4 xv = reinterpret_cast<const float4*>(x)[t];
    float4 hv = reinterpret_cast<const float4*>(h)[t];
    ushort4 xb = make_ushort4(f2bf(xv.x), f2bf(xv.y), f2bf(xv.z), f2bf(xv.w));
    ushort4 hb = make_ushort4(f2bf(hv.x), f2bf(hv.y), f2bf(hv.z), f2bf(hv.w));
    size_t base = (size_t)row * 2048 + c4;
    *reinterpret_cast<ushort4*>(XH + base) = xb;
    *reinterpret_cast<ushort4*>(XRH + base) = xb;
    *reinterpret_cast<ushort4*>(XH + base + 1024) = hb;
    return;
  }
  int t = (blockIdx.x - 8192) * blockDim.x + threadIdx.x;  // float4 index
  const int Q = 1024 * 2048 / 4;
  const float* src;
  unsigned short* dst;
  int i;
  if (t < Q) {
    src = Wz; dst = WZR; i = t;
  } else if (t < 2 * Q) {
    src = Wr; dst = WZR + 1024 * 2048; i = t - Q;
  } else if (t < 3 * Q) {
    src = Wh; dst = WHb; i = t - 2 * Q;
  } else {
    src = Wo; dst = WOb; i = t - 3 * Q;
    if (i >= 512 * 1024 / 4) return;
  }
  float4 v = reinterpret_cast<const float4*>(src)[i];
  reinterpret_cast<ushort4*>(dst)[i] =
      make_ushort4(f2bf(v.x), f2bf(v.y), f2bf(v.z), f2bf(v.w));
}

// ---------------------------------------------------------------------------
// 8-phase 256x256 GEMM: C = A[M x K] * Bw[N x K]^T.  EPI: 0=gates, 1=cand.
// ---------------------------------------------------------------------------
template <int EPI>
__global__ __launch_bounds__(512, 2) void k_gemm8(
    const unsigned short* __restrict__ A, const unsigned short* __restrict__ Bw,
    int K, const float* __restrict__ bias1, const float* __restrict__ bias2,
    const float* __restrict__ hprev, float* __restrict__ Zbuf,
    unsigned short* __restrict__ XRH, float* __restrict__ outHid,
    unsigned short* __restrict__ HID, float* __restrict__ outO) {
  // LDS ring: slot s (kstep mod 4): A region [256r x 32k] then B [256 x 32k],
  // each as 16 blocks of (16 rows x 32 k) with the verified 16x32 swizzle.
  __shared__ __align__(16) unsigned short S[4 * 16384];  // 128 KiB

  const int tid = threadIdx.x;
  const int wave = tid >> 6;
  const int lane = tid & 63;
  const int quad = lane >> 4;
  const int l16 = lane & 15;
  const int bm = blockIdx.x;
  const int bn = blockIdx.y;
  const int wn = (wave & 3) << 6;   // 0 / 64 / 128 / 192

  // staging lane map: inverse of slot(r,c) = ((r&7)^c) + 8*(r&3) + 32*(r>>3)
  const int g_ = lane & 7;
  const int rmid = (lane >> 3) & 3;
  const int sr = ((lane >> 5) << 3) + (g_ & 4) + rmid;
  const int sck = (g_ & 3) ^ rmid;

  const unsigned short* gA =
      A + (size_t)(bm * 256 + wave * 16 + sr) * K + sck * 8;
  const unsigned short* gB =
      Bw + (size_t)(bn * 256 + wave * 16 + sr) * K + sck * 8;
  const size_t gstep = (size_t)128 * K;  // rows +128 for the second issue

  // read-side swizzled element offset within a 16x32 block
  const int so = (((l16 & 7) ^ quad) << 3) + ((l16 & 3) << 6) + ((l16 >> 3) << 8);
  const int aoff = ((wave >> 2) << 3) * 512 + so;         // (wm/16)*512 + so
  const int boff = 8192 + ((wave & 3) << 2) * 512 + so;   // (wn/16)*512 + so

  floatx4 acc[8][4];
#pragma unroll
  for (int i = 0; i < 8; ++i)
#pragma unroll
    for (int j = 0; j < 4; ++j) acc[i][j] = floatx4{0.f, 0.f, 0.f, 0.f};

  auto stA = [&](int s, int ks) {
    unsigned short* d = S + s * 16384 + wave * 512;
    const unsigned short* g = gA + (size_t)ks * 32;
    gld16(g, d);
    gld16(g + gstep, d + 8 * 512);
  };
  auto stB = [&](int s, int ks) {
    unsigned short* d = S + s * 16384 + 8192 + wave * 512;
    const unsigned short* g = gB + (size_t)ks * 32;
    gld16(g, d);
    gld16(g + gstep, d + 8 * 512);
  };

  // two explicit fragment register sets (pipeline depth 2)
  bf16x8 afA[4], afB[4], bfA[4], bfB[4];
  auto dsA = [&](bf16x8* af, int s, int mh) {
#pragma unroll
    for (int j = 0; j < 4; ++j)
      af[j] = *reinterpret_cast<const bf16x8*>(S + s * 16384 + aoff +
                                               (mh * 4 + j) * 512);
  };
  auto dsB = [&](bf16x8* bf, int s) {
#pragma unroll
    for (int nt = 0; nt < 4; ++nt)
      bf[nt] = *reinterpret_cast<const bf16x8*>(S + s * 16384 + boff + nt * 512);
  };
  auto mfh = [&](const bf16x8* af, const bf16x8* bf, int mh) {
    __builtin_amdgcn_s_setprio(1);
#pragma unroll
    for (int j = 0; j < 4; ++j)
#pragma unroll
      for (int nt = 0; nt < 4; ++nt)
        acc[mh * 4 + j][nt] = __builtin_amdgcn_mfma_f32_16x16x32_bf16(
            af[j], bf[nt], acc[mh * 4 + j][nt], 0, 0, 0);
    __builtin_amdgcn_s_setprio(0);
  };

  // barriers carry lgkmcnt(0): prior phase's ds_reads (issued one full MFMA
  // window ago) must be complete before any wave can pass — closes the
  // cross-wave read-vs-stage-overwrite race at ~zero cost.
#define BARG() asm volatile("s_waitcnt lgkmcnt(0)\n\ts_barrier" ::: "memory")
#define WV4() \
  asm volatile("s_waitcnt vmcnt(4) lgkmcnt(0)\n\ts_barrier" ::: "memory")
#define WV0() \
  asm volatile("s_waitcnt vmcnt(0) lgkmcnt(0)\n\ts_barrier" ::: "memory")

  // prologue: stage ksteps 0,1,2; vmcnt(4) leaves {A2,B2} in flight (the
  // steady-state invariant); slots 0,1 retired -> readable.
  stA(0, 0); stB(0, 0);
  stA(1, 1); stB(1, 1);
  stA(2, 2); stB(2, 2);
  asm volatile("s_waitcnt vmcnt(4)\n\ts_barrier" ::: "memory");
  // preload fragment sets for phase 0 (slot0)
  dsA(afA, 0, 0);
  dsB(bfA, 0);

  const int NK = K >> 5;   // ksteps of 32
  const int NI = NK >> 2;  // 8-phase iterations (4 ksteps each)
  // Phase shape: {stage; (wait+)BAR; reads(p+1) -> other set; MFMA(p)}.
  // mfh(p) uses the set read during phase p-1; reads(p+1) overlap mfh(p)'s
  // pipe drain. vmcnt FIFO (waits p3/p7, vmcnt(4)):
  //  p3 retires {A2,B2,A3,B3} -> covers slot2 reads @p3/p4, slot3 @p5/p6
  //  p7 retires {A0',B0',A1',B1'} -> covers slot0' @p7/p0, slot1' @p1/p2
  for (int i = 0; i < NI; ++i) {
    const int ks = i << 2;
    const bool more = (i + 1 < NI);
    // p0: mfma kstep0 mh0                     | stage A(ks+3)->slot3
    stA(3, ks + 3);
    BARG();
    dsA(afB, 0, 1);                    // for p1
    mfh(afA, bfA, 0);
    // p1: mfma kstep0 mh1                     | stage B(ks+3)->slot3
    stB(3, ks + 3);
    BARG();
    dsA(afA, 1, 0); dsB(bfB, 1);       // for p2
    mfh(afB, bfA, 1);
    // p2: mfma kstep1 mh0                     | stage A(ks+4)->slot0
    if (more) stA(0, ks + 4);
    BARG();
    dsA(afB, 1, 1);                    // for p3
    mfh(afA, bfB, 0);
    // p3: mfma kstep1 mh1                     | stage B(ks+4)->slot0
    if (more) stB(0, ks + 4);
    if (more) { WV4(); } else { WV0(); }
    dsA(afA, 2, 0); dsB(bfA, 2);       // for p4 (slot2 just retired)
    mfh(afB, bfB, 1);
    // p4: mfma kstep2 mh0                     | stage A(ks+5)->slot1
    if (more) stA(1, ks + 5);
    BARG();
    dsA(afB, 2, 1);                    // for p5
    mfh(afA, bfA, 0);
    // p5: mfma kstep2 mh1                     | stage B(ks+5)->slot1
    if (more) stB(1, ks + 5);
    BARG();
    dsA(afA, 3, 0); dsB(bfB, 3);       // for p6 (slot3 retired @p3)
    mfh(afB, bfA, 1);
    // p6: mfma kstep3 mh0                     | stage A(ks+6)->slot2
    if (more) stA(2, ks + 6);
    BARG();
    dsA(afB, 3, 1);                    // for p7
    mfh(afA, bfB, 0);
    // p7: mfma kstep3 mh1                     | stage B(ks+6)->slot2
    if (more) stB(2, ks + 6);
    if (more) { WV4(); } else { BARG(); }
    if (more) { dsA(afA, 0, 0); dsB(bfA, 0); }  // for next p0 (slot0')
    mfh(afB, bfB, 1);
  }
#undef BARG
#undef WV4
#undef WV0

  // Epilogue. C/D layout: col = lane&15, row = quad*4 + reg.
  // nt innermost: each row's 4x64B output chunks issue contiguously.
  const int wm = (wave >> 2) << 7;  // 0 / 128
#pragma unroll
  for (int mt = 0; mt < 8; ++mt) {
#pragma unroll
    for (int r = 0; r < 4; ++r) {
      const int m = bm * 256 + wm + mt * 16 + quad * 4 + r;
#pragma unroll
      for (int nt = 0; nt < 4; ++nt) {
        const int n = bn * 256 + wn + nt * 16 + l16;
        if (EPI == 0) {
          const bool isz = (n < 1024);  // wave-uniform (wn 64-aligned)
          const int nn = isz ? n : n - 1024;
          const float bb = isz ? bias1[nn] : bias2[nn];
          float v = acc[mt][nt][r] + bb;
          float s = 1.f / (1.f + __expf(-v));
          if (isz) {
            Zbuf[(size_t)m * 1024 + nn] = s;  // fp32: no gate quantization
          } else {
            XRH[(size_t)m * 2048 + 1024 + nn] =
                f2bf(s * hprev[(size_t)m * 1024 + nn]);
          }
        } else {
          const float bb = bias1[n];
          float v = acc[mt][nt][r] + bb;
          float e = __expf(-2.f * v);
          float th = (1.f - e) / (1.f + e);
          float z = Zbuf[(size_t)m * 1024 + n];
          float hold = hprev[(size_t)m * 1024 + n];
          float hid = hold + z * (th - hold);
          outHid[(size_t)m * 1024 + n] = hid;
          HID[(size_t)m * 1024 + n] = f2bf(hid);
        }
      }
    }
  }
}

// ---------------------------------------------------------------------------
// R6 2-phase kernel: GEMM2 (EPI=1, TM=128) and GEMM3 (EPI=2, TM=64).
// ---------------------------------------------------------------------------
template <int EPI, int TM>
__global__ __launch_bounds__(256) void k_gemm(
    const unsigned short* __restrict__ A, const unsigned short* __restrict__ Bw,
    int K, const float* __restrict__ bias1, const float* __restrict__ bias2,
    const float* __restrict__ hprev, float* __restrict__ Zbuf,
    unsigned short* __restrict__ XRH, float* __restrict__ outHid,
    unsigned short* __restrict__ HID, float* __restrict__ outO) {
  constexpr int MT = TM / 32;            // m-frags per wave
  constexpr int BUF = TM * 32 + 4096;    // elems: A tile + B tile (128x32)
  constexpr int NLD = TM / 64 + 2;       // gld16 per thread per K-tile
  __shared__ __align__(16) unsigned short S[2 * BUF];

  const int tid = threadIdx.x;
  const int wave = tid >> 6;
  const int lane = tid & 63;
  const int bm = blockIdx.x;
  const int bn = blockIdx.y;
  const int wm = (wave >> 1) * (TM / 2);
  const int wn = (wave & 1) << 6;
  const int quad = lane >> 4;
  const int l16 = lane & 15;

  const int g_ = lane & 7;
  const int rmid = (lane >> 3) & 3;
  const int sr = (lane >> 5) * 8 + (g_ & 4) + rmid;
  const int sck = (g_ & 3) ^ rmid;
  const int arow0 = wave * (TM / 4);
  const int brow0 = wave * 32;
  const unsigned short* gA = A + (size_t)(bm * TM + arow0 + sr) * K + sck * 8;
  const unsigned short* gB = Bw + (size_t)(bn * 128 + brow0 + sr) * K + sck * 8;
  const size_t row16 = (size_t)16 * K;

  const int so = (((l16 & 7) ^ quad) << 3) + ((l16 & 3) << 6) + ((l16 >> 3) << 8);

  floatx4 acc[MT][4];
#pragma unroll
  for (int i = 0; i < MT; ++i)
#pragma unroll
    for (int j = 0; j < 4; ++j) acc[i][j] = floatx4{0.f, 0.f, 0.f, 0.f};

  auto stage = [&](int buf, int kk) {
    unsigned short* b = S + buf * BUF;
    const unsigned short* ga = gA + (size_t)kk * 32;
    const unsigned short* gb = gB + (size_t)kk * 32;
#pragma unroll
    for (int g = 0; g < TM / 64; ++g)
      gld16(ga + g * row16, b + (arow0 + g * 16) * 32);
#pragma unroll
    for (int g = 0; g < 2; ++g)
      gld16(gb + g * row16, b + TM * 32 + (brow0 + g * 16) * 32);
  };

  auto compute = [&](int buf) {
    const unsigned short* base = S + buf * BUF;
    bf16x8 af[MT], bfr[4];
#pragma unroll
    for (int mt = 0; mt < MT; ++mt)
      af[mt] = *reinterpret_cast<const bf16x8*>(base + ((wm + mt * 16) << 5) + so);
#pragma unroll
    for (int nt = 0; nt < 4; ++nt)
      bfr[nt] = *reinterpret_cast<const bf16x8*>(base + TM * 32 +
                                                 ((wn + nt * 16) << 5) + so);
#pragma unroll
    for (int mt = 0; mt < MT; ++mt)
#pragma unroll
      for (int nt = 0; nt < 4; ++nt)
        acc[mt][nt] = __builtin_amdgcn_mfma_f32_16x16x32_bf16(af[mt], bfr[nt],
                                                              acc[mt][nt], 0, 0, 0);
  };

  auto waitbarN = [&]() {
    if constexpr (NLD == 4)
      asm volatile("s_waitcnt vmcnt(4)\n\ts_barrier" ::: "memory");
    else
      asm volatile("s_waitcnt vmcnt(3)\n\ts_barrier" ::: "memory");
  };
  auto waitbar0 = [&]() {
    asm volatile("s_waitcnt vmcnt(0)\n\ts_barrier" ::: "memory");
  };
  auto endbar = [&]() {
    asm volatile("s_waitcnt lgkmcnt(0)\n\ts_barrier" ::: "memory");
  };

  const int NB = K >> 5;
  stage(0, 0);
  stage(1, 1);
  for (int k = 0; k < NB; k += 2) {
    waitbarN();
    compute(0);
    endbar();
    if (k + 2 < NB) stage(0, k + 2);
    if (k + 2 < NB) waitbarN(); else waitbar0();
    compute(1);
    endbar();
    if (k + 3 < NB) stage(1, k + 3);
  }

  // Epilogue, nt innermost for write-combining.
#pragma unroll
  for (int mt = 0; mt < MT; ++mt) {
#pragma unroll
    for (int r = 0; r < 4; ++r) {
      const int m = bm * TM + wm + mt * 16 + quad * 4 + r;
#pragma unroll
      for (int nt = 0; nt < 4; ++nt) {
        const int n = bn * 128 + wn + nt * 16 + l16;
        if (EPI == 0) {
          const bool isz = (n < 1024);
          const int nn = isz ? n : n - 1024;
          const float bb = isz ? bias1[nn] : bias2[nn];
          float v = acc[mt][nt][r] + bb;
          float s = 1.f / (1.f + __expf(-v));
          if (isz) {
            Zbuf[(size_t)m * 1024 + nn] = s;
          } else {
            XRH[(size_t)m * 2048 + 1024 + nn] =
                f2bf(s * hprev[(size_t)m * 1024 + nn]);
          }
        } else if (EPI == 1) {
          const float bb = bias1[n];
          float v = acc[mt][nt][r] + bb;
          float e = __expf(-2.f * v);
          float th = (1.f - e) / (1.f + e);
          float z = Zbuf[(size_t)m * 1024 + n];
          float hold = hprev[(size_t)m * 1024 + n];
          float hid = hold + z * (th - hold);
          outHid[(size_t)m * 1024 + n] = hid;
          HID[(size_t)m * 1024 + n] = f2bf(hid);
        } else {
          const float bb = bias1[n];
          outO[(size_t)m * 512 + n] = acc[mt][nt][r] + bb;
        }
      }
    }
  }
}

extern "C" void kernel_launch(void* const* d_in, const int* in_sizes, int n_in,
                              void* d_out, int out_size, void* d_ws, size_t ws_size,
                              hipStream_t stream) {
  const float* x = (const float*)d_in[0];
  const float* h = (const float*)d_in[1];
  const float* Wz = (const float*)d_in[2];
  const float* bz = (const float*)d_in[3];
  const float* Wr = (const float*)d_in[4];
  const float* br = (const float*)d_in[5];
  const float* Wh = (const float*)d_in[6];
  const float* bh = (const float*)d_in[7];
  const float* Wo = (const float*)d_in[8];
  const float* bo = (const float*)d_in[9];

  float* outO = (float*)d_out;                // [8192,512]
  float* outHid = outO + (size_t)8192 * 512;  // [8192,1024]

  char* ws = (char*)d_ws;
  const size_t MB = 1u << 20;
  unsigned short* XH = (unsigned short*)(ws + 0 * MB);    // [8192][2048] bf16
  unsigned short* XRH = (unsigned short*)(ws + 32 * MB);  // [8192][2048] bf16
  unsigned short* WZR = (unsigned short*)(ws + 64 * MB);  // [2048][2048] bf16
  unsigned short* WHb = (unsigned short*)(ws + 72 * MB);  // [1024][2048] bf16
  unsigned short* WOb = (unsigned short*)(ws + 76 * MB);  // [512][1024]  bf16
  float* Zb = (float*)(ws + 80 * MB);                     // [8192][1024] fp32
  unsigned short* HID = XH;  // XH dead after GEMM1 — reuse as bf16 hidden

  // pack + cvt fused into one launch
  k_prep<<<14848, 256, 0, stream>>>(x, h, XH, XRH, Wz, Wr, Wh, Wo, WZR, WHb,
                                    WOb);

  // GEMM 1: z|r fused (M=8192, N=2048, K=2048) — 8-phase 256x256, 256 blocks
  k_gemm8<0><<<dim3(32, 8), 512, 0, stream>>>(
      XH, WZR, 2048, bz, br, h, Zb, XRH, nullptr, nullptr, nullptr);
  // GEMM 2: candidate + combine (N=1024) — 2-phase 128^2, 512 blocks (R6)
  k_gemm<1, 128><<<dim3(64, 8), 256, 0, stream>>>(
      XRH, WHb, 2048, bh, nullptr, h, Zb, nullptr, outHid, HID, nullptr);
  // GEMM 3: output projection (N=512), 2-phase TM=64, 512 blocks
  k_gemm<2, 64><<<dim3(128, 4), 256, 0, stream>>>(
      HID, WOb, 1024, bo, nullptr, nullptr, nullptr, nullptr, nullptr, nullptr,
      outO);
}

// Round 6
// 302.441 us; speedup vs baseline: 1.3668x; 1.3668x over previous
//
#include <hip/hip_runtime.h>

// GRU cell, B=8192, IN=H=1024, OUT=512 — bf16 MFMA pipeline.
// R12: (1) GEMM1 reverted to the exact R10 8-phase kernel (101.4us proven;
//  R11's frag double-buffer spilled to scratch: unified reg budget at
//  launch_bounds(512,2) is 256/wave = 128 AGPR acc + 128 VGPR, and +32 frag
//  regs pushed VGPR side over -> 120MB scratch traffic).
// (2) GEMM2 ported to a counted-vmcnt 4-phase 256x128 kernel, full grid
//  (32x8=256 blocks, 1/CU): per-wave 64x64 (acc=64 AGPR), 16 MFMA/phase,
//  8 ds_read_b128/phase, ring-of-4 slots (96 KiB), one full-slot stage
//  (3 gld16) per phase, s_waitcnt vmcnt(6) every phase. FIFO: each wait
//  retires exactly the slot read next phase; 2 stages stay in flight;
//  stage->retire ~3 phases >> HBM latency. Tail: vmcnt(3)/vmcnt(0).
// GEMM3 / k_prep / epilogue orders unchanged.

typedef __bf16 bf16x8 __attribute__((ext_vector_type(8)));
typedef float floatx4 __attribute__((ext_vector_type(4)));

__device__ __forceinline__ unsigned short f2bf(float f) {
  unsigned int u = __float_as_uint(f);
  u += 0x7fffu + ((u >> 16) & 1u);
  return (unsigned short)(u >> 16);
}

__device__ __forceinline__ void gld16(const void* g, void* l) {
  // async global->LDS, 16B/lane; LDS dest = wave-uniform base + lane*16
  __builtin_amdgcn_global_load_lds(
      (__attribute__((address_space(1))) void*)g,
      (__attribute__((address_space(3))) void*)l, 16, 0, 0);
}

// pack_xh (blocks 0..8191) + cvt_all (blocks 8192..14847) in one launch
__global__ void k_prep(const float* __restrict__ x, const float* __restrict__ h,
                       unsigned short* __restrict__ XH,
                       unsigned short* __restrict__ XRH,
                       const float* __restrict__ Wz, const float* __restrict__ Wr,
                       const float* __restrict__ Wh, const float* __restrict__ Wo,
                       unsigned short* __restrict__ WZR,
                       unsigned short* __restrict__ WHb,
                       unsigned short* __restrict__ WOb) {
  if (blockIdx.x < 8192) {
    int t = blockIdx.x * blockDim.x + threadIdx.x;
    int row = t >> 8;
    int c4 = (t & 255) << 2;
    float4 xv = reinterpret_cast<const float4*>(x)[t];
    float4 hv = reinterpret_cast<const float4*>(h)[t];
    ushort4 xb = make_ushort4(f2bf(xv.x), f2bf(xv.y), f2bf(xv.z), f2bf(xv.w));
    ushort4 hb = make_ushort4(f2bf(hv.x), f2bf(hv.y), f2bf(hv.z), f2bf(hv.w));
    size_t base = (size_t)row * 2048 + c4;
    *reinterpret_cast<ushort4*>(XH + base) = xb;
    *reinterpret_cast<ushort4*>(XRH + base) = xb;
    *reinterpret_cast<ushort4*>(XH + base + 1024) = hb;
    return;
  }
  int t = (blockIdx.x - 8192) * blockDim.x + threadIdx.x;  // float4 index
  const int Q = 1024 * 2048 / 4;
  const float* src;
  unsigned short* dst;
  int i;
  if (t < Q) {
    src = Wz; dst = WZR; i = t;
  } else if (t < 2 * Q) {
    src = Wr; dst = WZR + 1024 * 2048; i = t - Q;
  } else if (t < 3 * Q) {
    src = Wh; dst = WHb; i = t - 2 * Q;
  } else {
    src = Wo; dst = WOb; i = t - 3 * Q;
    if (i >= 512 * 1024 / 4) return;
  }
  float4 v = reinterpret_cast<const float4*>(src)[i];
  reinterpret_cast<ushort4*>(dst)[i] =
      make_ushort4(f2bf(v.x), f2bf(v.y), f2bf(v.z), f2bf(v.w));
}

// ---------------------------------------------------------------------------
// 8-phase 256x256 GEMM (R10, proven): C = A * Bw^T.  EPI: 0=gates.
// ---------------------------------------------------------------------------
template <int EPI>
__global__ __launch_bounds__(512, 2) void k_gemm8(
    const unsigned short* __restrict__ A, const unsigned short* __restrict__ Bw,
    int K, const float* __restrict__ bias1, const float* __restrict__ bias2,
    const float* __restrict__ hprev, float* __restrict__ Zbuf,
    unsigned short* __restrict__ XRH, float* __restrict__ outHid,
    unsigned short* __restrict__ HID, float* __restrict__ outO) {
  __shared__ __align__(16) unsigned short S[4 * 16384];  // 128 KiB

  const int tid = threadIdx.x;
  const int wave = tid >> 6;
  const int lane = tid & 63;
  const int quad = lane >> 4;
  const int l16 = lane & 15;
  const int bm = blockIdx.x;
  const int bn = blockIdx.y;
  const int wn = (wave & 3) << 6;   // 0 / 64 / 128 / 192

  const int g_ = lane & 7;
  const int rmid = (lane >> 3) & 3;
  const int sr = ((lane >> 5) << 3) + (g_ & 4) + rmid;
  const int sck = (g_ & 3) ^ rmid;

  const unsigned short* gA =
      A + (size_t)(bm * 256 + wave * 16 + sr) * K + sck * 8;
  const unsigned short* gB =
      Bw + (size_t)(bn * 256 + wave * 16 + sr) * K + sck * 8;
  const size_t gstep = (size_t)128 * K;

  const int so = (((l16 & 7) ^ quad) << 3) + ((l16 & 3) << 6) + ((l16 >> 3) << 8);
  const int aoff = ((wave >> 2) << 3) * 512 + so;
  const int boff = 8192 + ((wave & 3) << 2) * 512 + so;

  floatx4 acc[8][4];
#pragma unroll
  for (int i = 0; i < 8; ++i)
#pragma unroll
    for (int j = 0; j < 4; ++j) acc[i][j] = floatx4{0.f, 0.f, 0.f, 0.f};

  auto stA = [&](int s, int ks) {
    unsigned short* d = S + s * 16384 + wave * 512;
    const unsigned short* g = gA + (size_t)ks * 32;
    gld16(g, d);
    gld16(g + gstep, d + 8 * 512);
  };
  auto stB = [&](int s, int ks) {
    unsigned short* d = S + s * 16384 + 8192 + wave * 512;
    const unsigned short* g = gB + (size_t)ks * 32;
    gld16(g, d);
    gld16(g + gstep, d + 8 * 512);
  };

  bf16x8 af[4], bf[4];
  auto dsA = [&](int s, int mh) {
#pragma unroll
    for (int j = 0; j < 4; ++j)
      af[j] = *reinterpret_cast<const bf16x8*>(S + s * 16384 + aoff +
                                               (mh * 4 + j) * 512);
  };
  auto dsB = [&](int s) {
#pragma unroll
    for (int nt = 0; nt < 4; ++nt)
      bf[nt] = *reinterpret_cast<const bf16x8*>(S + s * 16384 + boff + nt * 512);
  };
  auto mfh = [&](int mh) {
    __builtin_amdgcn_s_setprio(1);
#pragma unroll
    for (int j = 0; j < 4; ++j)
#pragma unroll
      for (int nt = 0; nt < 4; ++nt)
        acc[mh * 4 + j][nt] = __builtin_amdgcn_mfma_f32_16x16x32_bf16(
            af[j], bf[nt], acc[mh * 4 + j][nt], 0, 0, 0);
    __builtin_amdgcn_s_setprio(0);
  };

#define BAR() asm volatile("s_barrier" ::: "memory")
#define WV4() asm volatile("s_waitcnt vmcnt(4)\n\ts_barrier" ::: "memory")
#define WV0() asm volatile("s_waitcnt vmcnt(0)\n\ts_barrier" ::: "memory")

  stA(0, 0); stB(0, 0);
  stA(1, 1); stB(1, 1);
  stA(2, 2); stB(2, 2);
  asm volatile("s_waitcnt vmcnt(4)\n\ts_barrier" ::: "memory");

  const int NK = K >> 5;
  const int NI = NK >> 2;
  for (int i = 0; i < NI; ++i) {
    const int ks = i << 2;
    const bool more = (i + 1 < NI);
    dsA(0, 0); dsB(0); stA(3, ks + 3);
    BAR(); mfh(0);
    dsA(0, 1); stB(3, ks + 3);
    BAR(); mfh(1);
    dsA(1, 0); dsB(1); if (more) stA(0, ks + 4);
    BAR(); mfh(0);
    dsA(1, 1); if (more) stB(0, ks + 4);
    if (more) { WV4(); } else { WV0(); }
    mfh(1);
    dsA(2, 0); dsB(2); if (more) stA(1, ks + 5);
    BAR(); mfh(0);
    dsA(2, 1); if (more) stB(1, ks + 5);
    BAR(); mfh(1);
    dsA(3, 0); dsB(3); if (more) stA(2, ks + 6);
    BAR(); mfh(0);
    dsA(3, 1); if (more) stB(2, ks + 6);
    if (more) { WV4(); } else { BAR(); }
    mfh(1);
  }
#undef BAR
#undef WV4
#undef WV0

  const int wm = (wave >> 2) << 7;
#pragma unroll
  for (int mt = 0; mt < 8; ++mt) {
#pragma unroll
    for (int r = 0; r < 4; ++r) {
      const int m = bm * 256 + wm + mt * 16 + quad * 4 + r;
#pragma unroll
      for (int nt = 0; nt < 4; ++nt) {
        const int n = bn * 256 + wn + nt * 16 + l16;
        if (EPI == 0) {
          const bool isz = (n < 1024);
          const int nn = isz ? n : n - 1024;
          const float bb = isz ? bias1[nn] : bias2[nn];
          float v = acc[mt][nt][r] + bb;
          float s = 1.f / (1.f + __expf(-v));
          if (isz) {
            Zbuf[(size_t)m * 1024 + nn] = s;
          } else {
            XRH[(size_t)m * 2048 + 1024 + nn] =
                f2bf(s * hprev[(size_t)m * 1024 + nn]);
          }
        } else {
          const float bb = bias1[n];
          float v = acc[mt][nt][r] + bb;
          float e = __expf(-2.f * v);
          float th = (1.f - e) / (1.f + e);
          float z = Zbuf[(size_t)m * 1024 + n];
          float hold = hprev[(size_t)m * 1024 + n];
          float hid = hold + z * (th - hold);
          outHid[(size_t)m * 1024 + n] = hid;
          HID[(size_t)m * 1024 + n] = f2bf(hid);
        }
      }
    }
  }
}

// ---------------------------------------------------------------------------
// 4-phase 256x128 GEMM for GEMM2 (candidate+combine), full 256-block grid.
// Per wave 64x64 (acc=64), 16 MFMA/phase, ring-4 slots, vmcnt(6)/phase.
// ---------------------------------------------------------------------------
__global__ __launch_bounds__(512, 2) void k_gemm4(
    const unsigned short* __restrict__ A, const unsigned short* __restrict__ Bw,
    int K, const float* __restrict__ bias1, const float* __restrict__ hprev,
    float* __restrict__ Zbuf, float* __restrict__ outHid,
    unsigned short* __restrict__ HID) {
  constexpr int SLOT = 12288;  // shorts: A 256x32 (8192) + B 128x32 (4096)
  __shared__ __align__(16) unsigned short S[4 * SLOT];  // 96 KiB

  const int tid = threadIdx.x;
  const int wave = tid >> 6;
  const int lane = tid & 63;
  const int quad = lane >> 4;
  const int l16 = lane & 15;
  const int bm = blockIdx.x;
  const int bn = blockIdx.y;
  const int wmi = wave >> 1;  // 0..3
  const int wni = wave & 1;   // 0..1
  const int wm = wmi << 6;    // 0/64/128/192
  const int wn = wni << 6;    // 0/64

  // staging lane map (inverse of slot(r,c) swizzle) — same as k_gemm8
  const int g_ = lane & 7;
  const int rmid = (lane >> 3) & 3;
  const int sr = ((lane >> 5) << 3) + (g_ & 4) + rmid;
  const int sck = (g_ & 3) ^ rmid;

  const unsigned short* gA =
      A + (size_t)(bm * 256 + wave * 16 + sr) * K + sck * 8;
  const unsigned short* gB =
      Bw + (size_t)(bn * 128 + wave * 16 + sr) * K + sck * 8;
  const size_t gstep = (size_t)128 * K;

  const int so = (((l16 & 7) ^ quad) << 3) + ((l16 & 3) << 6) + ((l16 >> 3) << 8);
  const int aoff = (wmi << 2) * 512 + so;
  const int boff = 8192 + (wni << 2) * 512 + so;

  floatx4 acc[4][4];
#pragma unroll
  for (int i = 0; i < 4; ++i)
#pragma unroll
    for (int j = 0; j < 4; ++j) acc[i][j] = floatx4{0.f, 0.f, 0.f, 0.f};

  // full-slot stage: A rows {wave*16, +128} (2 gld16) + B rows wave*16 (1)
  auto stage = [&](int s, int ks) {
    unsigned short* d = S + s * SLOT;
    const unsigned short* ga = gA + (size_t)ks * 32;
    gld16(ga, d + wave * 512);
    gld16(ga + gstep, d + (wave + 8) * 512);
    gld16(gB + (size_t)ks * 32, d + 8192 + wave * 512);
  };

  bf16x8 af[4], bf[4];
  auto rd = [&](int s) {
    const unsigned short* base = S + s * SLOT;
#pragma unroll
    for (int t = 0; t < 4; ++t) {
      af[t] = *reinterpret_cast<const bf16x8*>(base + aoff + t * 512);
      bf[t] = *reinterpret_cast<const bf16x8*>(base + boff + t * 512);
    }
  };
  auto mf = [&]() {
    __builtin_amdgcn_s_setprio(1);
#pragma unroll
    for (int mt = 0; mt < 4; ++mt)
#pragma unroll
      for (int nt = 0; nt < 4; ++nt)
        acc[mt][nt] = __builtin_amdgcn_mfma_f32_16x16x32_bf16(af[mt], bf[nt],
                                                              acc[mt][nt], 0, 0, 0);
    __builtin_amdgcn_s_setprio(0);
  };

#define BAR() asm volatile("s_barrier" ::: "memory")
#define WV6() asm volatile("s_waitcnt vmcnt(6)\n\ts_barrier" ::: "memory")
#define WV3() asm volatile("s_waitcnt vmcnt(3)\n\ts_barrier" ::: "memory")
#define WV0() asm volatile("s_waitcnt vmcnt(0)\n\ts_barrier" ::: "memory")

  // prologue: stage slots 0,1,2 (9 loads); vmcnt(6) retires slot0.
  stage(0, 0);
  stage(1, 1);
  stage(2, 2);
  WV6();

  const int NK = K >> 5;   // 64 ksteps
  const int NI = NK >> 2;  // 16 iterations of 4 phases
  // Phase p: {rd(slot); stage(next); WAIT+BAR; 16 MFMA}. vmcnt(6) leaves
  // 2 full-slot stages (6 loads) in flight; each wait retires exactly the
  // slot read in the NEXT phase (FIFO verified); stage->retire ~3 phases.
  for (int i = 0; i < NI; ++i) {
    const int ks = i << 2;
    const bool more = (i + 1 < NI);
    // p0: read slot0 (ks+0) | stage slot3 <- ks+3
    rd(0); stage(3, ks + 3);
    WV6(); mf();
    // p1: read slot1 (ks+1) | stage slot0 <- ks+4
    rd(1); if (more) stage(0, ks + 4);
    if (more) { WV6(); } else { WV3(); }
    mf();
    // p2: read slot2 (ks+2) | stage slot1 <- ks+5
    rd(2); if (more) stage(1, ks + 5);
    if (more) { WV6(); } else { WV0(); }
    mf();
    // p3: read slot3 (ks+3) | stage slot2 <- ks+6
    rd(3); if (more) stage(2, ks + 6);
    if (more) { WV6(); } else { BAR(); }
    mf();
  }
#undef BAR
#undef WV6
#undef WV3
#undef WV0

  // Epilogue (candidate + combine), nt innermost for write-combining.
#pragma unroll
  for (int mt = 0; mt < 4; ++mt) {
#pragma unroll
    for (int r = 0; r < 4; ++r) {
      const int m = bm * 256 + wm + mt * 16 + quad * 4 + r;
#pragma unroll
      for (int nt = 0; nt < 4; ++nt) {
        const int n = bn * 128 + wn + nt * 16 + l16;
        const float bb = bias1[n];
        float v = acc[mt][nt][r] + bb;
        float e = __expf(-2.f * v);
        float th = (1.f - e) / (1.f + e);
        float z = Zbuf[(size_t)m * 1024 + n];
        float hold = hprev[(size_t)m * 1024 + n];
        float hid = hold + z * (th - hold);
        outHid[(size_t)m * 1024 + n] = hid;
        HID[(size_t)m * 1024 + n] = f2bf(hid);
      }
    }
  }
}

// ---------------------------------------------------------------------------
// R6 2-phase kernel: GEMM3 (EPI=2, TM=64).
// ---------------------------------------------------------------------------
template <int EPI, int TM>
__global__ __launch_bounds__(256) void k_gemm(
    const unsigned short* __restrict__ A, const unsigned short* __restrict__ Bw,
    int K, const float* __restrict__ bias1, const float* __restrict__ bias2,
    const float* __restrict__ hprev, float* __restrict__ Zbuf,
    unsigned short* __restrict__ XRH, float* __restrict__ outHid,
    unsigned short* __restrict__ HID, float* __restrict__ outO) {
  constexpr int MT = TM / 32;
  constexpr int BUF = TM * 32 + 4096;
  constexpr int NLD = TM / 64 + 2;
  __shared__ __align__(16) unsigned short S[2 * BUF];

  const int tid = threadIdx.x;
  const int wave = tid >> 6;
  const int lane = tid & 63;
  const int bm = blockIdx.x;
  const int bn = blockIdx.y;
  const int wm = (wave >> 1) * (TM / 2);
  const int wn = (wave & 1) << 6;
  const int quad = lane >> 4;
  const int l16 = lane & 15;

  const int g_ = lane & 7;
  const int rmid = (lane >> 3) & 3;
  const int sr = (lane >> 5) * 8 + (g_ & 4) + rmid;
  const int sck = (g_ & 3) ^ rmid;
  const int arow0 = wave * (TM / 4);
  const int brow0 = wave * 32;
  const unsigned short* gA = A + (size_t)(bm * TM + arow0 + sr) * K + sck * 8;
  const unsigned short* gB = Bw + (size_t)(bn * 128 + brow0 + sr) * K + sck * 8;
  const size_t row16 = (size_t)16 * K;

  const int so = (((l16 & 7) ^ quad) << 3) + ((l16 & 3) << 6) + ((l16 >> 3) << 8);

  floatx4 acc[MT][4];
#pragma unroll
  for (int i = 0; i < MT; ++i)
#pragma unroll
    for (int j = 0; j < 4; ++j) acc[i][j] = floatx4{0.f, 0.f, 0.f, 0.f};

  auto stage = [&](int buf, int kk) {
    unsigned short* b = S + buf * BUF;
    const unsigned short* ga = gA + (size_t)kk * 32;
    const unsigned short* gb = gB + (size_t)kk * 32;
#pragma unroll
    for (int g = 0; g < TM / 64; ++g)
      gld16(ga + g * row16, b + (arow0 + g * 16) * 32);
#pragma unroll
    for (int g = 0; g < 2; ++g)
      gld16(gb + g * row16, b + TM * 32 + (brow0 + g * 16) * 32);
  };

  auto compute = [&](int buf) {
    const unsigned short* base = S + buf * BUF;
    bf16x8 af[MT], bfr[4];
#pragma unroll
    for (int mt = 0; mt < MT; ++mt)
      af[mt] = *reinterpret_cast<const bf16x8*>(base + ((wm + mt * 16) << 5) + so);
#pragma unroll
    for (int nt = 0; nt < 4; ++nt)
      bfr[nt] = *reinterpret_cast<const bf16x8*>(base + TM * 32 +
                                                 ((wn + nt * 16) << 5) + so);
#pragma unroll
    for (int mt = 0; mt < MT; ++mt)
#pragma unroll
      for (int nt = 0; nt < 4; ++nt)
        acc[mt][nt] = __builtin_amdgcn_mfma_f32_16x16x32_bf16(af[mt], bfr[nt],
                                                              acc[mt][nt], 0, 0, 0);
  };

  auto waitbarN = [&]() {
    if constexpr (NLD == 4)
      asm volatile("s_waitcnt vmcnt(4)\n\ts_barrier" ::: "memory");
    else
      asm volatile("s_waitcnt vmcnt(3)\n\ts_barrier" ::: "memory");
  };
  auto waitbar0 = [&]() {
    asm volatile("s_waitcnt vmcnt(0)\n\ts_barrier" ::: "memory");
  };
  auto endbar = [&]() {
    asm volatile("s_waitcnt lgkmcnt(0)\n\ts_barrier" ::: "memory");
  };

  const int NB = K >> 5;
  stage(0, 0);
  stage(1, 1);
  for (int k = 0; k < NB; k += 2) {
    waitbarN();
    compute(0);
    endbar();
    if (k + 2 < NB) stage(0, k + 2);
    if (k + 2 < NB) waitbarN(); else waitbar0();
    compute(1);
    endbar();
    if (k + 3 < NB) stage(1, k + 3);
  }

#pragma unroll
  for (int mt = 0; mt < MT; ++mt) {
#pragma unroll
    for (int r = 0; r < 4; ++r) {
      const int m = bm * TM + wm + mt * 16 + quad * 4 + r;
#pragma unroll
      for (int nt = 0; nt < 4; ++nt) {
        const int n = bn * 128 + wn + nt * 16 + l16;
        if (EPI == 0) {
          const bool isz = (n < 1024);
          const int nn = isz ? n : n - 1024;
          const float bb = isz ? bias1[nn] : bias2[nn];
          float v = acc[mt][nt][r] + bb;
          float s = 1.f / (1.f + __expf(-v));
          if (isz) {
            Zbuf[(size_t)m * 1024 + nn] = s;
          } else {
            XRH[(size_t)m * 2048 + 1024 + nn] =
                f2bf(s * hprev[(size_t)m * 1024 + nn]);
          }
        } else if (EPI == 1) {
          const float bb = bias1[n];
          float v = acc[mt][nt][r] + bb;
          float e = __expf(-2.f * v);
          float th = (1.f - e) / (1.f + e);
          float z = Zbuf[(size_t)m * 1024 + n];
          float hold = hprev[(size_t)m * 1024 + n];
          float hid = hold + z * (th - hold);
          outHid[(size_t)m * 1024 + n] = hid;
          HID[(size_t)m * 1024 + n] = f2bf(hid);
        } else {
          const float bb = bias1[n];
          outO[(size_t)m * 512 + n] = acc[mt][nt][r] + bb;
        }
      }
    }
  }
}

extern "C" void kernel_launch(void* const* d_in, const int* in_sizes, int n_in,
                              void* d_out, int out_size, void* d_ws, size_t ws_size,
                              hipStream_t stream) {
  const float* x = (const float*)d_in[0];
  const float* h = (const float*)d_in[1];
  const float* Wz = (const float*)d_in[2];
  const float* bz = (const float*)d_in[3];
  const float* Wr = (const float*)d_in[4];
  const float* br = (const float*)d_in[5];
  const float* Wh = (const float*)d_in[6];
  const float* bh = (const float*)d_in[7];
  const float* Wo = (const float*)d_in[8];
  const float* bo = (const float*)d_in[9];

  float* outO = (float*)d_out;                // [8192,512]
  float* outHid = outO + (size_t)8192 * 512;  // [8192,1024]

  char* ws = (char*)d_ws;
  const size_t MB = 1u << 20;
  unsigned short* XH = (unsigned short*)(ws + 0 * MB);    // [8192][2048] bf16
  unsigned short* XRH = (unsigned short*)(ws + 32 * MB);  // [8192][2048] bf16
  unsigned short* WZR = (unsigned short*)(ws + 64 * MB);  // [2048][2048] bf16
  unsigned short* WHb = (unsigned short*)(ws + 72 * MB);  // [1024][2048] bf16
  unsigned short* WOb = (unsigned short*)(ws + 76 * MB);  // [512][1024]  bf16
  float* Zb = (float*)(ws + 80 * MB);                     // [8192][1024] fp32
  unsigned short* HID = XH;  // XH dead after GEMM1 — reuse as bf16 hidden

  // pack + cvt fused into one launch
  k_prep<<<14848, 256, 0, stream>>>(x, h, XH, XRH, Wz, Wr, Wh, Wo, WZR, WHb,
                                    WOb);

  // GEMM 1: z|r fused (M=8192, N=2048, K=2048) — 8-phase 256x256, 256 blocks
  k_gemm8<0><<<dim3(32, 8), 512, 0, stream>>>(
      XH, WZR, 2048, bz, br, h, Zb, XRH, nullptr, nullptr, nullptr);
  // GEMM 2: candidate + combine (N=1024) — 4-phase 256x128, 256 blocks
  k_gemm4<<<dim3(32, 8), 512, 0, stream>>>(XRH, WHb, 2048, bh, h, Zb, outHid,
                                           HID);
  // GEMM 3: output projection (N=512), 2-phase TM=64, 512 blocks
  k_gemm<2, 64><<<dim3(128, 4), 256, 0, stream>>>(
      HID, WOb, 1024, bo, nullptr, nullptr, nullptr, nullptr, nullptr, nullptr,
      outO);
}